// Round 4
// baseline (79.636 us; speedup 1.0000x reference)
//
#include <hip/hip_runtime.h>
#include <hip/hip_fp16.h>

// ComplexMixture: B=32, S=128, N=256
// Or[b,n,m] = sum_s w[b,s]*(r[b,s,n]*r[b,s,m] + i[b,s,n]*i[b,s,m])
// Oi[b,n,m] = sum_s w[b,s]*(i[b,s,n]*r[b,s,m] - r[b,s,n]*i[b,s,m])
//
// R4: single fused kernel. Each of 512 blocks (2/CU co-resident, 64KB LDS):
//   phase T: transpose+f16-convert its (b, s-chunk, n-chunk) into ws
//   flag handshake (device-scope acquire/release, flags zeroed by memsetAsync)
//   phase G: 64x64 MFMA tile; B-side staged via global_load_lds (linear dest,
//            inverse-swizzled per-lane source); A-side reg-staged w/ weights.
// XCD-grouping bid swizzle: all 16 blocks of a batch on one XCD (ws L2-local).

constexpr int B = 32, S = 128, N = 256;
constexpr unsigned FLAG_DONE = 1u;

typedef _Float16 f16x8 __attribute__((ext_vector_type(8)));
typedef float    f32x4 __attribute__((ext_vector_type(4)));

union F16x8 { f16x8 v; __half2 h2[4]; };

__device__ __forceinline__ void gld_lds16(const void* g, void* l) {
    __builtin_amdgcn_global_load_lds(
        (const __attribute__((address_space(1))) void*)g,
        (__attribute__((address_space(3))) void*)l, 16, 0, 0);
}

__global__ __launch_bounds__(256, 2) void ComplexMixture_71313636983193_kernel(
    const float* __restrict__ R, const float* __restrict__ I,
    const float* __restrict__ W, float* __restrict__ Or, float* __restrict__ Oi,
    _Float16* __restrict__ Rt, _Float16* __restrict__ It, unsigned* __restrict__ flags)
{
    __shared__ union alignas(16) {
        struct { _Float16 AWR[64][128], AWI[64][128], BR[64][128], BI[64][128]; } g;
        struct { float T1[32][68], T2[32][68]; } tb;
    } u;

    const int pb   = blockIdx.x;
    const int lbid = (pb & 7) * 64 + (pb >> 3);   // batch-group per XCD
    const int b  = lbid >> 4;
    const int ti = (lbid >> 2) & 3;
    const int tj = lbid & 3;
    const int t  = threadIdx.x;
    const int wv = t >> 6, lane = t & 63;

    // ---------------- Phase T: transpose + f16 convert my chunk ----------
    {
        const int s0  = ti * 32;
        const int n0T = tj * 64;
        const float* Rb = R + ((size_t)b * S + s0) * N + n0T;
        const float* Ib = I + ((size_t)b * S + s0) * N + n0T;

        #pragma unroll
        for (int p = 0; p < 2; ++p) {
            const int idx = t + p * 256;
            const int s = idx >> 4, q = idx & 15;
            const int qs = q ^ ((s >> 3) << 2);           // chunk swizzle
            *(float4*)&u.tb.T1[s][qs * 4] = *(const float4*)&Rb[s * N + q * 4];
            *(float4*)&u.tb.T2[s][qs * 4] = *(const float4*)&Ib[s * N + q * 4];
        }
        __syncthreads();

        const int n   = t >> 2;       // 0..63
        const int sq8 = t & 3;        // s-octet 0..3
        #pragma unroll
        for (int p = 0; p < 2; ++p) {
            const float (*Tp)[68] = p ? u.tb.T2 : u.tb.T1;
            float a[8];
            #pragma unroll
            for (int j = 0; j < 8; ++j) {
                const int s = sq8 * 8 + j;
                const int c = (n >> 2) ^ ((s >> 3) << 2);
                a[j] = Tp[s][c * 4 + (n & 3)];
            }
            F16x8 f;
            #pragma unroll
            for (int j = 0; j < 4; ++j)
                f.h2[j] = __floats2half2_rn(a[2 * j], a[2 * j + 1]);
            const size_t off = ((size_t)(b * N + n0T + n) * S) + s0 + sq8 * 8;
            *(f16x8*)((p ? It : Rt) + off) = f.v;
        }
    }

    // ---------------- publish my chunk, wait for the 8 I need ------------
    __threadfence();
    __syncthreads();
    if (t == 0)
        __hip_atomic_store(&flags[lbid], FLAG_DONE,
                           __ATOMIC_RELEASE, __HIP_MEMORY_SCOPE_AGENT);
    if (t < 8) {
        const int nc = (t & 1) ? tj : ti;
        const int sc = t >> 1;
        while (__hip_atomic_load(&flags[(b << 4) + (sc << 2) + nc],
                                 __ATOMIC_ACQUIRE, __HIP_MEMORY_SCOPE_AGENT) != FLAG_DONE)
            __builtin_amdgcn_s_sleep(2);
    }
    __syncthreads();
    asm volatile("" ::: "memory");

    // ---------------- Phase G: MFMA 64x64 tile ---------------------------
    const int n0 = ti * 64, m0 = tj * 64;
    const _Float16* Bmr = Rt + ((size_t)b * N + m0) * S;
    const _Float16* Bmi = It + ((size_t)b * N + m0) * S;

    // Async B staging: linear LDS dest, inverse-swizzled per-lane source.
    // LDS slot (row, ch) must hold logical chunk sq = ch ^ (row&7).
    #pragma unroll
    for (int i = 0; i < 4; ++i) {
        const int Xb   = wv * 4096 + i * 1024;        // wave-uniform base byte
        const int X    = Xb + lane * 16;              // this lane's LDS byte
        const int row  = X >> 8;
        const int sq_  = ((X >> 4) & 15) ^ (row & 7);
        const int srcO = row * 256 + sq_ * 16;        // bytes (row stride 256B)
        gld_lds16((const char*)Bmr + srcO, (char*)&u.g.BR[0][0] + Xb);
        gld_lds16((const char*)Bmi + srcO, (char*)&u.g.BI[0][0] + Xb);
    }

    // A staging: reg-staged, weight-scaled (per-thread weights, no barrier).
    {
        const _Float16* Anr = Rt + ((size_t)b * N + n0) * S;
        const _Float16* Ani = It + ((size_t)b * N + n0) * S;
        const float* Wb = W + b * S;
        const int sq = t & 15;
        const float4 w0 = *(const float4*)&Wb[sq * 8];
        const float4 w1 = *(const float4*)&Wb[sq * 8 + 4];
        const __half2 wh[4] = { __floats2half2_rn(w0.x, w0.y), __floats2half2_rn(w0.z, w0.w),
                                __floats2half2_rn(w1.x, w1.y), __floats2half2_rn(w1.z, w1.w) };
        #pragma unroll
        for (int p = 0; p < 4; ++p) {
            const int row = (t >> 4) + p * 16;
            const int sqs = sq ^ (row & 7);
            const size_t g = (size_t)row * S + sq * 8;
            F16x8 fr, fi;
            fr.v = *(const f16x8*)&Anr[g];
            fi.v = *(const f16x8*)&Ani[g];
            #pragma unroll
            for (int j = 0; j < 4; ++j) {
                fr.h2[j] = __hmul2(fr.h2[j], wh[j]);
                fi.h2[j] = __hmul2(fi.h2[j], wh[j]);
            }
            *(f16x8*)&u.g.AWR[row][sqs * 8] = fr.v;
            *(f16x8*)&u.g.AWI[row][sqs * 8] = fi.v;
        }
    }
    __syncthreads();   // drains vmcnt (DMA) + lgkm (A writes)

    // Compute: wave wv covers (wn, wm) 32x32 sub-tile.
    const int wn = (wv >> 1) * 32, wm = (wv & 1) * 32;
    const int fr16 = lane & 15, kb = lane >> 4;

    f32x4 accR[2][2] = {}, accA[2][2] = {}, accB[2][2] = {};

    #pragma unroll
    for (int ks = 0; ks < 4; ++ks) {
        const int K = ks * 4 + kb;
        f16x8 awr[2], awi[2], br[2], bi[2];
        #pragma unroll
        for (int ns = 0; ns < 2; ++ns) {
            const int ra = wn + ns * 16 + fr16;
            const int rb = wm + ns * 16 + fr16;
            const int ca = (K ^ (ra & 7)) * 8;
            const int cb = (K ^ (rb & 7)) * 8;
            awr[ns] = *(const f16x8*)&u.g.AWR[ra][ca];
            awi[ns] = *(const f16x8*)&u.g.AWI[ra][ca];
            br[ns]  = *(const f16x8*)&u.g.BR[rb][cb];
            bi[ns]  = *(const f16x8*)&u.g.BI[rb][cb];
        }
        #pragma unroll
        for (int ns = 0; ns < 2; ++ns) {
            #pragma unroll
            for (int ms = 0; ms < 2; ++ms) {
                accR[ns][ms] = __builtin_amdgcn_mfma_f32_16x16x32_f16(awr[ns], br[ms], accR[ns][ms], 0, 0, 0);
                accR[ns][ms] = __builtin_amdgcn_mfma_f32_16x16x32_f16(awi[ns], bi[ms], accR[ns][ms], 0, 0, 0);
                accA[ns][ms] = __builtin_amdgcn_mfma_f32_16x16x32_f16(awi[ns], br[ms], accA[ns][ms], 0, 0, 0);
                accB[ns][ms] = __builtin_amdgcn_mfma_f32_16x16x32_f16(awr[ns], bi[ms], accB[ns][ms], 0, 0, 0);
            }
        }
    }

    // Epilogue: C/D layout col = lane&15, row = (lane>>4)*4 + reg.
    #pragma unroll
    for (int ns = 0; ns < 2; ++ns) {
        #pragma unroll
        for (int ms = 0; ms < 2; ++ms) {
            #pragma unroll
            for (int r = 0; r < 4; ++r) {
                const int nn = n0 + wn + ns * 16 + kb * 4 + r;
                const int mm = m0 + wm + ms * 16 + fr16;
                const size_t o = ((size_t)b * N + nn) * N + mm;
                Or[o] = accR[ns][ms][r];
                Oi[o] = accA[ns][ms][r] - accB[ns][ms][r];
            }
        }
    }
}

extern "C" void kernel_launch(void* const* d_in, const int* in_sizes, int n_in,
                              void* d_out, int out_size, void* d_ws, size_t ws_size,
                              hipStream_t stream) {
    const float* R = (const float*)d_in[0];
    const float* I = (const float*)d_in[1];
    const float* W = (const float*)d_in[2];
    float* Or = (float*)d_out;
    float* Oi = (float*)d_out + (size_t)B * N * N;

    _Float16* Rt = (_Float16*)d_ws;
    _Float16* It = Rt + (size_t)B * N * S;                    // 2 MB each
    unsigned* flags = (unsigned*)((char*)d_ws + 4u * 1024 * 1024);

    hipMemsetAsync(flags, 0, 512 * sizeof(unsigned), stream); // fresh handshake per call
    ComplexMixture_71313636983193_kernel<<<dim3(512), dim3(256), 0, stream>>>(
        R, I, W, Or, Oi, Rt, It, flags);
}

// Round 6
// 16.753 us; speedup vs baseline: 4.7535x; 4.7535x over previous
//
#include <hip/hip_runtime.h>
#include <hip/hip_fp16.h>

// ComplexMixture: B=32, S=128, N=256
// Or[b,n,m] = sum_s w[b,s]*(r[b,s,n]*r[b,s,m] + i[b,s,n]*i[b,s,m])
// Oi[b,n,m] = sum_s w[b,s]*(i[b,s,n]*r[b,s,m] - r[b,s,n]*i[b,s,m])
//
// R6: single self-sufficient fused kernel (R4's cross-block handshake was a
// coherence storm; R5's tr_read lane-map was wrong). Each of 512 blocks:
//   - transposes its OWN A-chunk (n: ti*64, weighted) and B-chunk (m: tj*64)
//     f32->f16 into XOR-swizzled LDS tiles via an f32 LDS scratch
//     (16 s per iteration, 16 iterations; ~2x redundant vs R3's shared ws,
//     but reads are XCD-L2-resident and we drop a dispatch + 4MB ws trip)
//   - R3-proven swizzled ds_read_b128 fragment reads + 16x16x32 f16 MFMA.
// LDS: 64KB tiles + 8KB scratch = 72KB -> 2 blocks/CU.

constexpr int B = 32, S = 128, N = 256;

typedef _Float16 f16x8 __attribute__((ext_vector_type(8)));
typedef float    f32x4 __attribute__((ext_vector_type(4)));

union F16x8 { f16x8 v; __half2 h2[4]; };

__global__ __launch_bounds__(256, 2) void ComplexMixture_71313636983193_kernel(
    const float* __restrict__ R, const float* __restrict__ I,
    const float* __restrict__ W, float* __restrict__ Or, float* __restrict__ Oi)
{
    // f16 [64 rows][128 s], 16B chunks at swizzled pos chunk ^ (row&7)
    __shared__ alignas(16) _Float16 AWR[64][128];  // w*r, rows = n-chunk ti
    __shared__ alignas(16) _Float16 AWI[64][128];  // w*i
    __shared__ alignas(16) _Float16 BRt[64][128];  // r,  rows = m-chunk tj
    __shared__ alignas(16) _Float16 BIt[64][128];  // i
    // f32 transpose scratch [16 s][64 n], float4 chunks at pos q ^ ((s>>3)<<2)
    __shared__ alignas(16) float SR[16][64];
    __shared__ alignas(16) float SI[16][64];

    const int pb   = blockIdx.x;
    const int lbid = (pb & 7) * 64 + (pb >> 3);   // batch-group per XCD
    const int b  = lbid >> 4;
    const int ti = (lbid >> 2) & 3;               // A-side n-chunk
    const int tj = lbid & 3;                      // B-side m-chunk
    const int t  = threadIdx.x;
    const int wv = t >> 6, lane = t & 63;

    const float* Wb = W + b * S;

    // ---------------- Transpose phase: 16 iterations of 16 s -------------
    for (int it = 0; it < 16; ++it) {
        const int chunk = (it < 8) ? ti : tj;
        const int s0    = (it & 7) * 16;
        const float* Rs = R + ((size_t)b * S + s0) * N + chunk * 64;
        const float* Is = I + ((size_t)b * S + s0) * N + chunk * 64;

        // phase 1: coalesced float4 [16 s][64 n] -> scratch (swizzled chunks)
        #pragma unroll
        for (int p = 0; p < 2; ++p) {
            const int u  = t + p * 256;     // 0..511
            const int s  = (u >> 4) & 15;
            const int q  = u & 15;
            const int qs = q ^ ((s >> 3) << 2);
            const float4 v = *(const float4*)&((u >> 8) ? Is : Rs)[s * N + q * 4];
            *(float4*)&((u >> 8) ? SI : SR)[s][qs * 4] = v;
        }
        __syncthreads();

        // phase 2: gather 8 s for one n, weight (A side), convert, write tile
        {
            const int n   = t & 63;
            const int oct = (t >> 6) & 1;   // local s-octet
            const int arr = t >> 7;         // 0 = real, 1 = imag
            const float (*Sp)[64] = arr ? SI : SR;
            float a[8];
            #pragma unroll
            for (int j = 0; j < 8; ++j) {
                const int sl = oct * 8 + j;
                const int c  = (n >> 2) ^ ((sl >> 3) << 2);
                a[j] = Sp[sl][c * 4 + (n & 3)];
            }
            if (it < 8) {
                #pragma unroll
                for (int j = 0; j < 8; ++j)
                    a[j] *= Wb[s0 + oct * 8 + j];
            }
            F16x8 f;
            #pragma unroll
            for (int k = 0; k < 4; ++k)
                f.h2[k] = __floats2half2_rn(a[2 * k], a[2 * k + 1]);

            const int so  = (it & 7) * 2 + oct;   // global s-octet 0..15
            const int sqs = so ^ (n & 7);         // swizzled chunk
            _Float16 (*T)[128];
            if (it < 8) T = arr ? AWI : AWR;
            else        T = arr ? BIt : BRt;
            *(f16x8*)&T[n][sqs * 8] = f.v;
        }
        __syncthreads();
    }

    // ---------------- MFMA: wave wv covers (wn, wm) 32x32 sub-tile -------
    const int wn = (wv >> 1) * 32, wm = (wv & 1) * 32;
    const int fr16 = lane & 15, kb = lane >> 4;

    f32x4 accR[2][2] = {}, accA[2][2] = {}, accB[2][2] = {};

    #pragma unroll
    for (int ks = 0; ks < 4; ++ks) {
        const int K = ks * 4 + kb;
        f16x8 awr[2], awi[2], br[2], bi[2];
        #pragma unroll
        for (int ns = 0; ns < 2; ++ns) {
            const int ra = wn + ns * 16 + fr16;
            const int rb = wm + ns * 16 + fr16;
            const int ca = (K ^ (ra & 7)) * 8;
            const int cb = (K ^ (rb & 7)) * 8;
            awr[ns] = *(const f16x8*)&AWR[ra][ca];
            awi[ns] = *(const f16x8*)&AWI[ra][ca];
            br[ns]  = *(const f16x8*)&BRt[rb][cb];
            bi[ns]  = *(const f16x8*)&BIt[rb][cb];
        }
        #pragma unroll
        for (int ns = 0; ns < 2; ++ns) {
            #pragma unroll
            for (int ms = 0; ms < 2; ++ms) {
                accR[ns][ms] = __builtin_amdgcn_mfma_f32_16x16x32_f16(awr[ns], br[ms], accR[ns][ms], 0, 0, 0);
                accR[ns][ms] = __builtin_amdgcn_mfma_f32_16x16x32_f16(awi[ns], bi[ms], accR[ns][ms], 0, 0, 0);
                accA[ns][ms] = __builtin_amdgcn_mfma_f32_16x16x32_f16(awi[ns], br[ms], accA[ns][ms], 0, 0, 0);
                accB[ns][ms] = __builtin_amdgcn_mfma_f32_16x16x32_f16(awr[ns], bi[ms], accB[ns][ms], 0, 0, 0);
            }
        }
    }

    // ---------------- Epilogue: C/D col = lane&15, row = (lane>>4)*4+reg -
    const int n0 = ti * 64, m0 = tj * 64;
    #pragma unroll
    for (int ns = 0; ns < 2; ++ns) {
        #pragma unroll
        for (int ms = 0; ms < 2; ++ms) {
            #pragma unroll
            for (int r = 0; r < 4; ++r) {
                const int nn = n0 + wn + ns * 16 + kb * 4 + r;
                const int mm = m0 + wm + ms * 16 + fr16;
                const size_t o = ((size_t)b * N + nn) * N + mm;
                Or[o] = accR[ns][ms][r];
                Oi[o] = accA[ns][ms][r] - accB[ns][ms][r];
            }
        }
    }
}

extern "C" void kernel_launch(void* const* d_in, const int* in_sizes, int n_in,
                              void* d_out, int out_size, void* d_ws, size_t ws_size,
                              hipStream_t stream) {
    const float* R = (const float*)d_in[0];
    const float* I = (const float*)d_in[1];
    const float* W = (const float*)d_in[2];
    float* Or = (float*)d_out;
    float* Oi = (float*)d_out + (size_t)B * N * N;

    ComplexMixture_71313636983193_kernel<<<dim3(512), dim3(256), 0, stream>>>(
        R, I, W, Or, Oi);
}

// Round 7
// 14.509 us; speedup vs baseline: 5.4886x; 1.1546x over previous
//
#include <hip/hip_runtime.h>
#include <hip/hip_fp16.h>

// ComplexMixture: B=32, S=128, N=256
// Or[b,n,m] = sum_s w[b,s]*(r[b,s,n]*r[b,s,m] + i[b,s,n]*i[b,s,m])
// Oi[b,n,m] = sum_s w[b,s]*(i[b,s,n]*r[b,s,m] - r[b,s,n]*i[b,s,m])
//
// R7: one-shot register transpose. Each thread loads float4 pairs from rows
// (s, s+1) and packs (s,s+1) __half2 values directly into the swizzled f16
// tiles — no f32 LDS scratch, ONE barrier total (R6 had 32).
// Tile layout: [64 rows][16 chunks x 8 s]; logical chunk c of row x lives at
// slot c ^ ((x>>2)&15); natural s order inside a chunk. This swizzle makes
// staging b32 writes bank-uniform (2-way = free) and keeps fragment b128
// reads at the uniform minimum. Weights folded into A in f32 at stage time.
// LDS = 64KB -> 2 blocks/CU. XCD-grouped bid swizzle for L2 locality.

constexpr int B = 32, S = 128, N = 256;

typedef _Float16 f16x8 __attribute__((ext_vector_type(8)));
typedef float    f32x4 __attribute__((ext_vector_type(4)));

__global__ __launch_bounds__(256, 2) void ComplexMixture_71313636983193_kernel(
    const float* __restrict__ R, const float* __restrict__ I,
    const float* __restrict__ W, float* __restrict__ Or, float* __restrict__ Oi)
{
    __shared__ alignas(16) _Float16 AWR[64][128];  // w*r, rows = n-chunk ti
    __shared__ alignas(16) _Float16 AWI[64][128];  // w*i
    __shared__ alignas(16) _Float16 BRt[64][128];  // r,   rows = m-chunk tj
    __shared__ alignas(16) _Float16 BIt[64][128];  // i

    const int pb   = blockIdx.x;
    const int lbid = (pb & 7) * 64 + (pb >> 3);   // batch-group per XCD
    const int b  = lbid >> 4;
    const int ti = (lbid >> 2) & 3;               // A-side n-chunk
    const int tj = lbid & 3;                      // B-side m-chunk
    const int t  = threadIdx.x;
    const int wv = t >> 6, lane = t & 63;

    const int sp = t >> 4;   // s-pair subgroup 0..15
    const int nq = t & 15;   // n-quad 0..15

    const float* Wb = W + b * S;
    const size_t bb = (size_t)b * S * N;
    const float* RA = R + bb + ti * 64 + nq * 4;
    const float* IA = I + bb + ti * 64 + nq * 4;
    const float* RB = R + bb + tj * 64 + nq * 4;
    const float* IB = I + bb + tj * 64 + nq * 4;

    char* const tAWR = (char*)&AWR[0][0];
    char* const tAWI = (char*)&AWI[0][0];
    char* const tBR  = (char*)&BRt[0][0];
    char* const tBI  = (char*)&BIt[0][0];

    // ---------------- Staging: register transpose, no scratch ------------
    #pragma unroll
    for (int it = 0; it < 4; ++it) {
        const int P = it * 16 + sp;   // s-pair index 0..63
        const int s = 2 * P;
        const float w0 = Wb[s], w1 = Wb[s + 1];

        const float4 ra0 = *(const float4*)&RA[(size_t)s * N];
        const float4 ra1 = *(const float4*)&RA[(size_t)(s + 1) * N];
        const float4 ia0 = *(const float4*)&IA[(size_t)s * N];
        const float4 ia1 = *(const float4*)&IA[(size_t)(s + 1) * N];
        const float4 rb0 = *(const float4*)&RB[(size_t)s * N];
        const float4 rb1 = *(const float4*)&RB[(size_t)(s + 1) * N];
        const float4 ib0 = *(const float4*)&IB[(size_t)s * N];
        const float4 ib1 = *(const float4*)&IB[(size_t)(s + 1) * N];

        const float* pra0 = (const float*)&ra0;
        const float* pra1 = (const float*)&ra1;
        const float* pia0 = (const float*)&ia0;
        const float* pia1 = (const float*)&ia1;
        const float* prb0 = (const float*)&rb0;
        const float* prb1 = (const float*)&rb1;
        const float* pib0 = (const float*)&ib0;
        const float* pib1 = (const float*)&ib1;

        const int c  = P >> 2;   // logical chunk 0..15
        const int pp = P & 3;    // pair position within chunk

        #pragma unroll
        for (int j = 0; j < 4; ++j) {
            const int n   = nq * 4 + j;
            // slot = c ^ sigma(n), sigma(n) = (n>>2)&15 = nq
            const int off = n * 256 + ((c ^ nq) * 16) + pp * 4;
            *(__half2*)(tAWR + off) = __floats2half2_rn(w0 * pra0[j], w1 * pra1[j]);
            *(__half2*)(tAWI + off) = __floats2half2_rn(w0 * pia0[j], w1 * pia1[j]);
            *(__half2*)(tBR  + off) = __floats2half2_rn(prb0[j], prb1[j]);
            *(__half2*)(tBI  + off) = __floats2half2_rn(pib0[j], pib1[j]);
        }
    }
    __syncthreads();   // the only barrier

    // ---------------- MFMA: wave wv covers (wn, wm) 32x32 sub-tile -------
    const int wn = (wv >> 1) * 32, wm = (wv & 1) * 32;
    const int fr16 = lane & 15, kb = lane >> 4;

    f32x4 accR[2][2] = {}, accA[2][2] = {}, accB[2][2] = {};

    #pragma unroll
    for (int ks = 0; ks < 4; ++ks) {
        const int K = ks * 4 + kb;
        f16x8 awr[2], awi[2], br[2], bi[2];
        #pragma unroll
        for (int ns = 0; ns < 2; ++ns) {
            const int ra = wn + ns * 16 + fr16;
            const int rb = wm + ns * 16 + fr16;
            const int ca = (K ^ ((ra >> 2) & 15)) * 8;
            const int cb = (K ^ ((rb >> 2) & 15)) * 8;
            awr[ns] = *(const f16x8*)&AWR[ra][ca];
            awi[ns] = *(const f16x8*)&AWI[ra][ca];
            br[ns]  = *(const f16x8*)&BRt[rb][cb];
            bi[ns]  = *(const f16x8*)&BIt[rb][cb];
        }
        #pragma unroll
        for (int ns = 0; ns < 2; ++ns) {
            #pragma unroll
            for (int ms = 0; ms < 2; ++ms) {
                accR[ns][ms] = __builtin_amdgcn_mfma_f32_16x16x32_f16(awr[ns], br[ms], accR[ns][ms], 0, 0, 0);
                accR[ns][ms] = __builtin_amdgcn_mfma_f32_16x16x32_f16(awi[ns], bi[ms], accR[ns][ms], 0, 0, 0);
                accA[ns][ms] = __builtin_amdgcn_mfma_f32_16x16x32_f16(awi[ns], br[ms], accA[ns][ms], 0, 0, 0);
                accB[ns][ms] = __builtin_amdgcn_mfma_f32_16x16x32_f16(awr[ns], bi[ms], accB[ns][ms], 0, 0, 0);
            }
        }
    }

    // ---------------- Epilogue: C/D col = lane&15, row = (lane>>4)*4+reg -
    const int n0 = ti * 64, m0 = tj * 64;
    #pragma unroll
    for (int ns = 0; ns < 2; ++ns) {
        #pragma unroll
        for (int ms = 0; ms < 2; ++ms) {
            #pragma unroll
            for (int r = 0; r < 4; ++r) {
                const int nn = n0 + wn + ns * 16 + kb * 4 + r;
                const int mm = m0 + wm + ms * 16 + fr16;
                const size_t o = ((size_t)b * N + nn) * N + mm;
                Or[o] = accR[ns][ms][r];
                Oi[o] = accA[ns][ms][r] - accB[ns][ms][r];
            }
        }
    }
}

extern "C" void kernel_launch(void* const* d_in, const int* in_sizes, int n_in,
                              void* d_out, int out_size, void* d_ws, size_t ws_size,
                              hipStream_t stream) {
    const float* R = (const float*)d_in[0];
    const float* I = (const float*)d_in[1];
    const float* W = (const float*)d_in[2];
    float* Or = (float*)d_out;
    float* Oi = (float*)d_out + (size_t)B * N * N;

    ComplexMixture_71313636983193_kernel<<<dim3(512), dim3(256), 0, stream>>>(
        R, I, W, Or, Oi);
}

// Round 8
// 13.885 us; speedup vs baseline: 5.7353x; 1.0449x over previous
//
#include <hip/hip_runtime.h>
#include <hip/hip_fp16.h>

// ComplexMixture: B=32, S=128, N=256
// Or[b,n,m] = sum_s w[b,s]*(r[b,s,n]*r[b,s,m] + i[b,s,n]*i[b,s,m])
// Oi[b,n,m] = sum_s w[b,s]*(i[b,s,n]*r[b,s,m] - r[b,s,n]*i[b,s,m])
//
// R8: 512-thread blocks (16 waves/CU = 4/SIMD, was 2/SIMD — latency hiding)
// and full-chunk register transpose: each thread loads float2 from 8 rows
// (8 s x 2 n x {R,I}), packs complete 16B f16 chunks -> ds_write_b128.
// Swizzle sigma(n) = (n>>1)&7, slot = chunk ^ sigma: staging b128 writes are
// conflict-FREE (8-lane phases bijective over banks), fragment b128 reads
// 2-way (free). One barrier. setprio(1) around MFMA loop (cross-block
// stage/compute diversity). LDS 64KB, 2 blocks/CU. XCD-grouped bid swizzle.

constexpr int B = 32, S = 128, N = 256;

typedef _Float16 f16x8 __attribute__((ext_vector_type(8)));
typedef float    f32x4 __attribute__((ext_vector_type(4)));

union F16x8 { f16x8 v; __half2 h2[4]; };

__global__ __launch_bounds__(512, 4) void ComplexMixture_71313636983193_kernel(
    const float* __restrict__ R, const float* __restrict__ I,
    const float* __restrict__ W, float* __restrict__ Or, float* __restrict__ Oi)
{
    // T[0]=w*r (A rows), T[1]=w*i, T[2]=r (B rows), T[3]=i
    // row n, logical chunk c (8 s) at slot c ^ ((n>>1)&7)
    __shared__ alignas(16) _Float16 T[4][64][128];   // 64 KB

    const int pb   = blockIdx.x;
    const int lbid = (pb & 7) * 64 + (pb >> 3);   // batch-group per XCD
    const int b  = lbid >> 4;
    const int ti = (lbid >> 2) & 3;               // A-side n-chunk
    const int tj = lbid & 3;                      // B-side m-chunk
    const int t  = threadIdx.x;
    const int wv = t >> 6, lane = t & 63;

    const float* Wb = W + b * S;
    const size_t bb = (size_t)b * S * N;
    const float* baseR[2] = { R + bb + ti * 64, R + bb + tj * 64 };
    const float* baseI[2] = { I + bb + ti * 64, I + bb + tj * 64 };

    // ---------------- Staging: full-chunk register transpose -------------
    // 1024 tasks = side(2) x octet(16) x npair(32); 2 passes of 512.
    // side == pass for 512 threads (task>>9).
    #pragma unroll
    for (int pass = 0; pass < 2; ++pass) {
        const int task  = t + pass * 512;
        const int npair = task & 31;          // n-pair 0..31
        const int octet = (task >> 5) & 15;   // s-octet 0..15
        const int side  = task >> 9;          // 0=A, 1=B (== pass)
        const int s0    = octet * 8;

        const float* pR = baseR[side] + npair * 2;
        const float* pI = baseI[side] + npair * 2;

        float2 r2[8], i2[8];
        #pragma unroll
        for (int s = 0; s < 8; ++s) {
            r2[s] = *(const float2*)&pR[(size_t)(s0 + s) * N];
            i2[s] = *(const float2*)&pI[(size_t)(s0 + s) * N];
        }

        float w8[8];
        if (side == 0) {
            #pragma unroll
            for (int s = 0; s < 8; ++s) w8[s] = Wb[s0 + s];
        }

        const int slot = octet ^ (npair & 7);
        #pragma unroll
        for (int j = 0; j < 2; ++j) {          // two n columns of the float2
            const int n = npair * 2 + j;
            F16x8 fr, fi;
            if (side == 0) {
                #pragma unroll
                for (int k = 0; k < 4; ++k) {
                    const float a0 = j ? r2[2*k].y : r2[2*k].x;
                    const float a1 = j ? r2[2*k+1].y : r2[2*k+1].x;
                    const float c0 = j ? i2[2*k].y : i2[2*k].x;
                    const float c1 = j ? i2[2*k+1].y : i2[2*k+1].x;
                    fr.h2[k] = __floats2half2_rn(w8[2*k] * a0, w8[2*k+1] * a1);
                    fi.h2[k] = __floats2half2_rn(w8[2*k] * c0, w8[2*k+1] * c1);
                }
            } else {
                #pragma unroll
                for (int k = 0; k < 4; ++k) {
                    const float a0 = j ? r2[2*k].y : r2[2*k].x;
                    const float a1 = j ? r2[2*k+1].y : r2[2*k+1].x;
                    const float c0 = j ? i2[2*k].y : i2[2*k].x;
                    const float c1 = j ? i2[2*k+1].y : i2[2*k+1].x;
                    fr.h2[k] = __floats2half2_rn(a0, a1);
                    fi.h2[k] = __floats2half2_rn(c0, c1);
                }
            }
            *(f16x8*)&T[side * 2 + 0][n][slot * 8] = fr.v;
            *(f16x8*)&T[side * 2 + 1][n][slot * 8] = fi.v;
        }
    }
    __syncthreads();   // the only barrier

    // ---------------- MFMA: wave = 16 (n) x 32 (m) sub-tile --------------
    const int wn = (wv & 3) * 16;    // A row group
    const int wm = (wv >> 2) * 32;   // B row group (2 x 16)
    const int fr16 = lane & 15, kb = lane >> 4;
    const int ra = wn + fr16;

    f32x4 accR[2] = {}, accA[2] = {}, accB[2] = {};

    __builtin_amdgcn_s_setprio(1);
    #pragma unroll
    for (int ks = 0; ks < 4; ++ks) {
        const int K  = ks * 4 + kb;
        const int ca = (K ^ ((ra >> 1) & 7)) * 8;
        const f16x8 awr = *(const f16x8*)&T[0][ra][ca];
        const f16x8 awi = *(const f16x8*)&T[1][ra][ca];
        #pragma unroll
        for (int ms = 0; ms < 2; ++ms) {
            const int rb = wm + ms * 16 + fr16;
            const int cb = (K ^ ((rb >> 1) & 7)) * 8;
            const f16x8 br = *(const f16x8*)&T[2][rb][cb];
            const f16x8 bi = *(const f16x8*)&T[3][rb][cb];
            accR[ms] = __builtin_amdgcn_mfma_f32_16x16x32_f16(awr, br, accR[ms], 0, 0, 0);
            accR[ms] = __builtin_amdgcn_mfma_f32_16x16x32_f16(awi, bi, accR[ms], 0, 0, 0);
            accA[ms] = __builtin_amdgcn_mfma_f32_16x16x32_f16(awi, br, accA[ms], 0, 0, 0);
            accB[ms] = __builtin_amdgcn_mfma_f32_16x16x32_f16(awr, bi, accB[ms], 0, 0, 0);
        }
    }
    __builtin_amdgcn_s_setprio(0);

    // ---------------- Epilogue: C/D col = lane&15, row = kb*4 + r --------
    const int n0 = ti * 64, m0 = tj * 64;
    const int nn = n0 + wn + kb * 4;
    #pragma unroll
    for (int ms = 0; ms < 2; ++ms) {
        const int mm = m0 + wm + ms * 16 + fr16;
        #pragma unroll
        for (int r = 0; r < 4; ++r) {
            const size_t o = ((size_t)b * N + nn + r) * N + mm;
            Or[o] = accR[ms][r];
            Oi[o] = accA[ms][r] - accB[ms][r];
        }
    }
}

extern "C" void kernel_launch(void* const* d_in, const int* in_sizes, int n_in,
                              void* d_out, int out_size, void* d_ws, size_t ws_size,
                              hipStream_t stream) {
    const float* R = (const float*)d_in[0];
    const float* I = (const float*)d_in[1];
    const float* W = (const float*)d_in[2];
    float* Or = (float*)d_out;
    float* Oi = (float*)d_out + (size_t)B * N * N;

    ComplexMixture_71313636983193_kernel<<<dim3(512), dim3(512), 0, stream>>>(
        R, I, W, Or, Oi);
}

// Round 9
// 12.994 us; speedup vs baseline: 6.1287x; 1.0686x over previous
//
#include <hip/hip_runtime.h>
#include <hip/hip_fp16.h>

// ComplexMixture: B=32, S=128, N=256
// Or[b,n,m] = sum_s w[b,s]*(r[b,s,n]*r[b,s,m] + i[b,s,n]*i[b,s,m])
// Oi[b,n,m] = sum_s w[b,s]*(i[b,s,n]*r[b,s,m] - r[b,s,n]*i[b,s,m])
//
// R9: K-half software pipeline inside one block (R8 was lockstep serial):
//   load H0 -> cvt+write H0 -> issue H1 loads -> bar -> MFMA ks0-1 (H1 loads
//   in flight) -> cvt+write H1 -> bar -> MFMA ks2-3 with ms-split stores.
// Chunk slots c^sigma for c=0..7 vs 8..15 are disjoint (bit 3), so H1 writes
// race-free against H0 fragment reads between the two barriers.
// Staging: float4 loads (4 n x 8 s per thread per half), full-chunk b128
// writes; sigma(n) = (n>>1)&7 keeps b128 writes & reads at uniform 8/phase.
// 512 threads, 64 KB LDS -> 2 blocks/CU, 4 waves/SIMD.

constexpr int B = 32, S = 128, N = 256;

typedef _Float16 f16x8 __attribute__((ext_vector_type(8)));
typedef float    f32x4 __attribute__((ext_vector_type(4)));

union F16x8 { f16x8 v; __half2 h2[4]; };

#define MFMA16(a, bv, c) __builtin_amdgcn_mfma_f32_16x16x32_f16((a), (bv), (c), 0, 0, 0)

__global__ __launch_bounds__(512, 4) void ComplexMixture_71313636983193_kernel(
    const float* __restrict__ R, const float* __restrict__ I,
    const float* __restrict__ W, float* __restrict__ Or, float* __restrict__ Oi)
{
    // T[0]=w*r (A rows), T[1]=w*i, T[2]=r (B rows), T[3]=i
    // row n, logical chunk c (8 s) at slot c ^ ((n>>1)&7)
    __shared__ alignas(16) _Float16 T[4][64][128];   // 64 KB

    const int pb   = blockIdx.x;
    const int lbid = (pb & 7) * 64 + (pb >> 3);   // batch-group per XCD
    const int b  = lbid >> 4;
    const int ti = (lbid >> 2) & 3;               // A-side n-chunk
    const int tj = lbid & 3;                      // B-side m-chunk
    const int t  = threadIdx.x;
    const int wv = t >> 6, lane = t & 63;

    // staging task: 512 = nquad(16) x octet(8) x side(2) x arr(2)
    const int nquad = t & 15;          // n = nquad*4 + j
    const int octet = (t >> 4) & 7;    // s-octet within K-half
    const int side  = (t >> 7) & 1;    // 0 = A(ti), 1 = B(tj)  (wave-uniform)
    const int arr   = t >> 8;          // 0 = real, 1 = imag    (wave-uniform)

    const size_t bb = (size_t)b * S * N;
    const int chunk = side ? tj : ti;
    const float* src = (arr ? I : R) + bb + chunk * 64 + nquad * 4;
    const float* Wb  = W + b * S;

    _Float16 (* const Td)[128] = T[side * 2 + arr];

    // ---- issue H0 loads (s = octet*8 + 0..7) ----
    float4 f0[8];
    #pragma unroll
    for (int s = 0; s < 8; ++s)
        f0[s] = *(const float4*)&src[(size_t)(octet * 8 + s) * N];

    float w0[8], w1[8];
    if (side == 0) {
        const float4 a0 = *(const float4*)&Wb[octet * 8];
        const float4 a1 = *(const float4*)&Wb[octet * 8 + 4];
        const float4 a2 = *(const float4*)&Wb[64 + octet * 8];
        const float4 a3 = *(const float4*)&Wb[64 + octet * 8 + 4];
        w0[0]=a0.x; w0[1]=a0.y; w0[2]=a0.z; w0[3]=a0.w;
        w0[4]=a1.x; w0[5]=a1.y; w0[6]=a1.z; w0[7]=a1.w;
        w1[0]=a2.x; w1[1]=a2.y; w1[2]=a2.z; w1[3]=a2.w;
        w1[4]=a3.x; w1[5]=a3.y; w1[6]=a3.z; w1[7]=a3.w;
    }

    // ---- convert + write H0 (chunk c = octet) ----
    #pragma unroll
    for (int j = 0; j < 4; ++j) {
        const int n    = nquad * 4 + j;
        const int slot = octet ^ ((n >> 1) & 7);
        F16x8 f;
        #pragma unroll
        for (int k = 0; k < 4; ++k) {
            float lo = ((const float*)&f0[2 * k])[j];
            float hi = ((const float*)&f0[2 * k + 1])[j];
            if (side == 0) { lo *= w0[2 * k]; hi *= w0[2 * k + 1]; }
            f.h2[k] = __floats2half2_rn(lo, hi);
        }
        *(f16x8*)&Td[n][slot * 8] = f.v;
    }

    // ---- issue H1 loads (s = 64 + octet*8 + 0..7); fly during MFMA H0 ----
    float4 f1[8];
    #pragma unroll
    for (int s = 0; s < 8; ++s)
        f1[s] = *(const float4*)&src[(size_t)(64 + octet * 8 + s) * N];

    __syncthreads();   // H0 tiles visible

    // ---- MFMA geometry (R8-proven): wave = 16(n) x 32(m) sub-tile ----
    const int wn = (wv & 3) * 16;
    const int wm = (wv >> 2) * 32;
    const int fr16 = lane & 15, kb = lane >> 4;
    const int ra  = wn + fr16;          const int sa  = (ra  >> 1) & 7;
    const int rb0 = wm + fr16;          const int sb0 = (rb0 >> 1) & 7;
    const int rb1 = wm + 16 + fr16;     const int sb1 = (rb1 >> 1) & 7;

    f32x4 accR[2] = {}, accA[2] = {}, accB[2] = {};
    f16x8 awr, awi;

#define LOAD_A(ks) { const int ca = (((ks) * 4 + kb) ^ sa) * 8;              \
        awr = *(const f16x8*)&T[0][ra][ca];                                  \
        awi = *(const f16x8*)&T[1][ra][ca]; }
#define STEP_B(ks, ms) { const int K = (ks) * 4 + kb;                        \
        const int rb = (ms) ? rb1 : rb0;                                     \
        const int cb = (K ^ ((ms) ? sb1 : sb0)) * 8;                         \
        const f16x8 br = *(const f16x8*)&T[2][rb][cb];                       \
        const f16x8 bi = *(const f16x8*)&T[3][rb][cb];                       \
        accR[ms] = MFMA16(awr, br, accR[ms]);                                \
        accR[ms] = MFMA16(awi, bi, accR[ms]);                                \
        accA[ms] = MFMA16(awi, br, accA[ms]);                                \
        accB[ms] = MFMA16(awr, bi, accB[ms]); }

    // ---- MFMA over H0 (ks = 0,1) ----
    __builtin_amdgcn_s_setprio(1);
    LOAD_A(0); STEP_B(0, 0); STEP_B(0, 1);
    LOAD_A(1); STEP_B(1, 0); STEP_B(1, 1);
    __builtin_amdgcn_s_setprio(0);

    // ---- convert + write H1 (chunk c = 8+octet; slots disjoint from H0) ----
    #pragma unroll
    for (int j = 0; j < 4; ++j) {
        const int n    = nquad * 4 + j;
        const int slot = (8 + octet) ^ ((n >> 1) & 7);
        F16x8 f;
        #pragma unroll
        for (int k = 0; k < 4; ++k) {
            float lo = ((const float*)&f1[2 * k])[j];
            float hi = ((const float*)&f1[2 * k + 1])[j];
            if (side == 0) { lo *= w1[2 * k]; hi *= w1[2 * k + 1]; }
            f.h2[k] = __floats2half2_rn(lo, hi);
        }
        *(f16x8*)&Td[n][slot * 8] = f.v;
    }

    __syncthreads();   // H1 tiles visible

    const int n0 = ti * 64, m0 = tj * 64;
    const int nn = n0 + wn + kb * 4;

#define STORE_MS(ms) {                                                       \
        const int mm = m0 + wm + (ms) * 16 + fr16;                           \
        _Pragma("unroll")                                                    \
        for (int r = 0; r < 4; ++r) {                                        \
            const size_t o = ((size_t)b * N + nn + r) * N + mm;              \
            Or[o] = accR[ms][r];                                             \
            Oi[o] = accA[ms][r] - accB[ms][r];                               \
        } }

    // ---- MFMA over H1 (ks = 2,3) with ms-split stores ----
    __builtin_amdgcn_s_setprio(1);
    LOAD_A(2); STEP_B(2, 0); STEP_B(2, 1);
    LOAD_A(3); STEP_B(3, 0);
    __builtin_amdgcn_s_setprio(0);
    STORE_MS(0);                 // HBM drain starts while ms=1 finishes
    __builtin_amdgcn_s_setprio(1);
    STEP_B(3, 1);
    __builtin_amdgcn_s_setprio(0);
    STORE_MS(1);
}

extern "C" void kernel_launch(void* const* d_in, const int* in_sizes, int n_in,
                              void* d_out, int out_size, void* d_ws, size_t ws_size,
                              hipStream_t stream) {
    const float* R = (const float*)d_in[0];
    const float* I = (const float*)d_in[1];
    const float* W = (const float*)d_in[2];
    float* Or = (float*)d_out;
    float* Oi = (float*)d_out + (size_t)B * N * N;

    ComplexMixture_71313636983193_kernel<<<dim3(512), dim3(512), 0, stream>>>(
        R, I, W, Or, Oi);
}

// Round 10
// 12.840 us; speedup vs baseline: 6.2022x; 1.0120x over previous
//
#include <hip/hip_runtime.h>
#include <hip/hip_fp16.h>

// ComplexMixture: B=32, S=128, N=256
// Or[b,n,m] = sum_s w[b,s]*(r[b,s,n]*r[b,s,m] + i[b,s,n]*i[b,s,m])
// Oi[b,n,m] = sum_s w[b,s]*(i[b,s,n]*r[b,s,m] - r[b,s,n]*i[b,s,m])
//
// R10: sequential two-tile blocks to hide the end-of-kernel store drain
// (R9's dominant exposed cost). 256 blocks x 512 threads; block computes
// tiles (ti, 2u) and (ti, 2u+1) of one batch, sharing the weighted A-side:
//   issue A+B1 loads -> cvt/write A,B1 -> issue B2 loads -> bar
//   -> MFMA tile1 (B2 loads fly) -> issue tile1 stores -> cvt/write B2
//   -> bar -> MFMA tile2 (tile1 stores drain underneath; ms-split)
//   -> tile2 stores.
// LDS 96 KB (A 32 + B1 32 + B2 32) -> 1 block/CU. R9-proven swizzle
// (slot = chunk ^ ((n>>1)&7)), staging, MFMA geometry and epilogue.

constexpr int B = 32, S = 128, N = 256;

typedef _Float16 f16x8 __attribute__((ext_vector_type(8)));
typedef float    f32x4 __attribute__((ext_vector_type(4)));

union F16x8 { f16x8 v; __half2 h2[4]; };

#define MFMA16(a, bv, c) __builtin_amdgcn_mfma_f32_16x16x32_f16((a), (bv), (c), 0, 0, 0)

__global__ __launch_bounds__(512, 2) void ComplexMixture_71313636983193_kernel(
    const float* __restrict__ R, const float* __restrict__ I,
    const float* __restrict__ W, float* __restrict__ Or, float* __restrict__ Oi)
{
    // T[0..1] = w*r, w*i (A rows = n-chunk ti)
    // T[2..3] = r, i (B rows = m-chunk tj1);  T[4..5] = r, i (m-chunk tj2)
    // row n, logical chunk c (8 s) at slot c ^ ((n>>1)&7)
    __shared__ alignas(16) _Float16 T[6][64][128];   // 96 KB

    const int pb   = blockIdx.x;
    const int lbid = (pb & 7) * 32 + (pb >> 3);   // 4 batches per XCD
    const int b   = lbid >> 3;
    const int rem = lbid & 7;
    const int ti  = rem >> 1;          // A-side n-chunk
    const int uu  = rem & 1;
    const int tj1 = uu * 2, tj2 = uu * 2 + 1;   // the two B-side m-chunks

    const int t  = threadIdx.x;
    const int wv = t >> 6, lane = t & 63;

    // staging task: 512 = nquad(16) x octet(16) x arr(2)
    const int nquad = t & 15;          // n = nquad*4 + j
    const int octet = (t >> 4) & 15;   // s-octet 0..15 (full K)
    const int arr   = t >> 8;          // 0 = real, 1 = imag (wave-uniform)
    const int s0    = octet * 8;

    const size_t bb = (size_t)b * S * N;
    const float* base  = (arr ? I : R) + bb + nquad * 4;
    const float* srcA  = base + ti  * 64;
    const float* srcB1 = base + tj1 * 64;
    const float* srcB2 = base + tj2 * 64;
    const float* Wb = W + b * S;

    // ---- issue A + B1 loads (8 rows of 4 n each) ----
    float4 fA[8], fB1[8];
    #pragma unroll
    for (int s = 0; s < 8; ++s)
        fA[s] = *(const float4*)&srcA[(size_t)(s0 + s) * N];
    #pragma unroll
    for (int s = 0; s < 8; ++s)
        fB1[s] = *(const float4*)&srcB1[(size_t)(s0 + s) * N];

    float w8[8];
    {
        const float4 a0 = *(const float4*)&Wb[s0];
        const float4 a1 = *(const float4*)&Wb[s0 + 4];
        w8[0]=a0.x; w8[1]=a0.y; w8[2]=a0.z; w8[3]=a0.w;
        w8[4]=a1.x; w8[5]=a1.y; w8[6]=a1.z; w8[7]=a1.w;
    }

    // ---- cvt + write A (weighted) and B1 ----
    #pragma unroll
    for (int j = 0; j < 4; ++j) {
        const int n    = nquad * 4 + j;
        const int slot = octet ^ ((n >> 1) & 7);
        F16x8 fa, fb;
        #pragma unroll
        for (int k = 0; k < 4; ++k) {
            fa.h2[k] = __floats2half2_rn(((const float*)&fA[2*k])[j]   * w8[2*k],
                                         ((const float*)&fA[2*k+1])[j] * w8[2*k+1]);
            fb.h2[k] = __floats2half2_rn(((const float*)&fB1[2*k])[j],
                                         ((const float*)&fB1[2*k+1])[j]);
        }
        *(f16x8*)&T[arr][n][slot * 8]     = fa.v;
        *(f16x8*)&T[2 + arr][n][slot * 8] = fb.v;
    }

    // ---- issue B2 loads; they fly during tile1 MFMA ----
    float4 fB2[8];
    #pragma unroll
    for (int s = 0; s < 8; ++s)
        fB2[s] = *(const float4*)&srcB2[(size_t)(s0 + s) * N];

    __syncthreads();   // A, B1 visible

    // ---- MFMA geometry (R9-proven): wave = 16(n) x 32(m) sub-tile ----
    const int wn = (wv & 3) * 16;
    const int wm = (wv >> 2) * 32;
    const int fr16 = lane & 15, kb = lane >> 4;
    const int ra  = wn + fr16;          const int sa  = (ra  >> 1) & 7;
    const int rb0 = wm + fr16;          const int sb0 = (rb0 >> 1) & 7;
    const int rb1 = wm + 16 + fr16;     const int sb1 = (rb1 >> 1) & 7;

    f16x8 awr, awi;

#define LOAD_A(ks) { const int ca = (((ks) * 4 + kb) ^ sa) * 8;              \
        awr = *(const f16x8*)&T[0][ra][ca];                                  \
        awi = *(const f16x8*)&T[1][ra][ca]; }
#define STEP_B(TB, ks, ms, aR, aA, aB) { const int K = (ks) * 4 + kb;        \
        const int rb = (ms) ? rb1 : rb0;                                     \
        const int cb = (K ^ ((ms) ? sb1 : sb0)) * 8;                         \
        const f16x8 br = *(const f16x8*)&T[TB][rb][cb];                      \
        const f16x8 bi = *(const f16x8*)&T[(TB) + 1][rb][cb];                \
        aR[ms] = MFMA16(awr, br, aR[ms]);                                    \
        aR[ms] = MFMA16(awi, bi, aR[ms]);                                    \
        aA[ms] = MFMA16(awi, br, aA[ms]);                                    \
        aB[ms] = MFMA16(awr, bi, aB[ms]); }

    const int n0 = ti * 64;
    const int nn = n0 + wn + kb * 4;

#define STORE_MS(TJ, ms, aR, aA, aB) {                                       \
        const int mm = (TJ) * 64 + wm + (ms) * 16 + fr16;                    \
        _Pragma("unroll")                                                    \
        for (int r = 0; r < 4; ++r) {                                        \
            const size_t o = ((size_t)b * N + nn + r) * N + mm;              \
            Or[o] = aR[ms][r];                                               \
            Oi[o] = aA[ms][r] - aB[ms][r];                                   \
        } }

    // ---- tile 1: full-K MFMA ----
    {
        f32x4 acR[2] = {}, acA[2] = {}, acB[2] = {};
        __builtin_amdgcn_s_setprio(1);
        LOAD_A(0); STEP_B(2, 0, 0, acR, acA, acB); STEP_B(2, 0, 1, acR, acA, acB);
        LOAD_A(1); STEP_B(2, 1, 0, acR, acA, acB); STEP_B(2, 1, 1, acR, acA, acB);
        LOAD_A(2); STEP_B(2, 2, 0, acR, acA, acB); STEP_B(2, 2, 1, acR, acA, acB);
        LOAD_A(3); STEP_B(2, 3, 0, acR, acA, acB); STEP_B(2, 3, 1, acR, acA, acB);
        __builtin_amdgcn_s_setprio(0);

        // issue tile1 stores now — they drain under B2 staging + tile2 MFMA
        STORE_MS(tj1, 0, acR, acA, acB);
        STORE_MS(tj1, 1, acR, acA, acB);
    }

    // ---- cvt + write B2 (own buffer, no WAR with tile1 reads) ----
    #pragma unroll
    for (int j = 0; j < 4; ++j) {
        const int n    = nquad * 4 + j;
        const int slot = octet ^ ((n >> 1) & 7);
        F16x8 fb;
        #pragma unroll
        for (int k = 0; k < 4; ++k)
            fb.h2[k] = __floats2half2_rn(((const float*)&fB2[2*k])[j],
                                         ((const float*)&fB2[2*k+1])[j]);
        *(f16x8*)&T[4 + arr][n][slot * 8] = fb.v;
    }

    __syncthreads();   // B2 visible

    // ---- tile 2: ms-split so the final drain is halved ----
    {
        f32x4 acR[2] = {}, acA[2] = {}, acB[2] = {};
        __builtin_amdgcn_s_setprio(1);
        LOAD_A(0); STEP_B(4, 0, 0, acR, acA, acB);
        LOAD_A(1); STEP_B(4, 1, 0, acR, acA, acB);
        LOAD_A(2); STEP_B(4, 2, 0, acR, acA, acB);
        LOAD_A(3); STEP_B(4, 3, 0, acR, acA, acB);
        __builtin_amdgcn_s_setprio(0);
        STORE_MS(tj2, 0, acR, acA, acB);
        __builtin_amdgcn_s_setprio(1);
        LOAD_A(0); STEP_B(4, 0, 1, acR, acA, acB);
        LOAD_A(1); STEP_B(4, 1, 1, acR, acA, acB);
        LOAD_A(2); STEP_B(4, 2, 1, acR, acA, acB);
        LOAD_A(3); STEP_B(4, 3, 1, acR, acA, acB);
        __builtin_amdgcn_s_setprio(0);
        STORE_MS(tj2, 1, acR, acA, acB);
    }
}

extern "C" void kernel_launch(void* const* d_in, const int* in_sizes, int n_in,
                              void* d_out, int out_size, void* d_ws, size_t ws_size,
                              hipStream_t stream) {
    const float* R = (const float*)d_in[0];
    const float* I = (const float*)d_in[1];
    const float* W = (const float*)d_in[2];
    float* Or = (float*)d_out;
    float* Oi = (float*)d_out + (size_t)B * N * N;

    ComplexMixture_71313636983193_kernel<<<dim3(256), dim3(512), 0, stream>>>(
        R, I, W, Or, Oi);
}